// Round 1
// baseline (10080.428 us; speedup 1.0000x reference)
//
#include <hip/hip_runtime.h>
#include <math.h>

#define NN 50000
#define NE 800000
#define HD 64

// ---------------- ws layout (floats) ----------------
// state : [0, NN*64)
// agg   : [NN*64, 2*NN*64)
// W2t   : [2*NN*64, +4096)      W2t[j*64+k] = W2[k*64+j]
// Wiht  : next 12288            Wiht[c*64+k] = W_ih[k*192+c]
// Whht  : next 12288            Whht[c*64+k] = W_hh[k*192+c]

__global__ __launch_bounds__(256) void prep_transpose(
    const float* __restrict__ W2, const float* __restrict__ Wih,
    const float* __restrict__ Whh,
    float* __restrict__ W2t, float* __restrict__ Wiht, float* __restrict__ Whht)
{
    int i = blockIdx.x * 256 + threadIdx.x;
    if (i < 64 * 64) {
        int k = i >> 6, j = i & 63;
        W2t[j * 64 + k] = W2[i];
    }
    if (i < 64 * 192) {
        int k = i / 192, c = i % 192;
        Wiht[c * 64 + k] = Wih[i];
        Whht[c * 64 + k] = Whh[i];
    }
}

__global__ __launch_bounds__(256) void init_state(
    const float* __restrict__ b, const float* __restrict__ W_in,
    const float* __restrict__ b_in,
    float* __restrict__ state, float* __restrict__ agg)
{
    int idx = blockIdx.x * 256 + threadIdx.x;
    if (idx >= NN * 64) return;
    int n = idx >> 6, j = idx & 63;
    state[idx] = b[n] * (W_in[j] - W_in[64 + j]) + b_in[j];
    agg[idx] = 0.f;
}

// One thread per edge. Weights read with wave-uniform addresses (scalar path).
// h1[64], m[64] in registers, all statically indexed.
__global__ __launch_bounds__(256) void edge_mlp(
    const int* __restrict__ mn, const float* __restrict__ Jm,
    const float* __restrict__ bb,
    const float* __restrict__ W1, const float* __restrict__ b1,
    const float* __restrict__ W2t, const float* __restrict__ b2,
    const float* __restrict__ W3, const float* __restrict__ b3,
    const float* __restrict__ state, float* __restrict__ agg)
{
    int e = blockIdx.x * 256 + threadIdx.x;   // grid is exact: 3125*256 == NE
    int ein = mn[2 * e], eout = mn[2 * e + 1];
    float bi = bb[ein], bo = bb[eout], J = Jm[e];

    float h1[64];
#pragma unroll
    for (int j = 0; j < 64; j++) h1[j] = b1[j];

    const float4* si = reinterpret_cast<const float4*>(state + (size_t)ein * 64);
    const float4* so = reinterpret_cast<const float4*>(state + (size_t)eout * 64);

    // x = [s_in(0..63), ff_in(64..67), s_out(68..131), ff_out(132..135)]
    for (int t = 0; t < 16; t++) {
        float4 a = si[t];
        {
            const float* w = W1 + (4 * t + 0) * 64;
#pragma unroll
            for (int j = 0; j < 64; j++) h1[j] += a.x * w[j];
        }
        {
            const float* w = W1 + (4 * t + 1) * 64;
#pragma unroll
            for (int j = 0; j < 64; j++) h1[j] += a.y * w[j];
        }
        {
            const float* w = W1 + (4 * t + 2) * 64;
#pragma unroll
            for (int j = 0; j < 64; j++) h1[j] += a.z * w[j];
        }
        {
            const float* w = W1 + (4 * t + 3) * 64;
#pragma unroll
            for (int j = 0; j < 64; j++) h1[j] += a.w * w[j];
        }
    }
    {
        float xv[4] = { bi, -bi, J, -J };
#pragma unroll
        for (int u = 0; u < 4; u++) {
            const float* w = W1 + (64 + u) * 64;
            float x = xv[u];
#pragma unroll
            for (int j = 0; j < 64; j++) h1[j] += x * w[j];
        }
    }
    for (int t = 0; t < 16; t++) {
        float4 a = so[t];
        {
            const float* w = W1 + (68 + 4 * t + 0) * 64;
#pragma unroll
            for (int j = 0; j < 64; j++) h1[j] += a.x * w[j];
        }
        {
            const float* w = W1 + (68 + 4 * t + 1) * 64;
#pragma unroll
            for (int j = 0; j < 64; j++) h1[j] += a.y * w[j];
        }
        {
            const float* w = W1 + (68 + 4 * t + 2) * 64;
#pragma unroll
            for (int j = 0; j < 64; j++) h1[j] += a.z * w[j];
        }
        {
            const float* w = W1 + (68 + 4 * t + 3) * 64;
#pragma unroll
            for (int j = 0; j < 64; j++) h1[j] += a.w * w[j];
        }
    }
    {
        float xv[4] = { -bo, bo, -J, J };
#pragma unroll
        for (int u = 0; u < 4; u++) {
            const float* w = W1 + (132 + u) * 64;
            float x = xv[u];
#pragma unroll
            for (int j = 0; j < 64; j++) h1[j] += x * w[j];
        }
    }
#pragma unroll
    for (int j = 0; j < 64; j++) h1[j] = fmaxf(h1[j], 0.f);

    // fused layer2 (relu) + layer3: m = relu(h1@W2+b2)@W3 + b3
    float m[64];
#pragma unroll
    for (int j = 0; j < 64; j++) m[j] = b3[j];
    for (int j = 0; j < 64; j++) {           // uniform loop
        float h2 = b2[j];
        const float* w2 = W2t + j * 64;      // contiguous: W2[:,j]
#pragma unroll
        for (int k = 0; k < 64; k++) h2 += h1[k] * w2[k];
        h2 = fmaxf(h2, 0.f);
        const float* w3 = W3 + j * 64;       // contiguous: W3[j,:]
#pragma unroll
        for (int jj = 0; jj < 64; jj++) m[jj] += h2 * w3[jj];
    }

    float* ar = agg + (size_t)eout * 64;
#pragma unroll
    for (int j = 0; j < 64; j++) atomicAdd(ar + j, m[j]);
}

// GRU: 2 threads per node (j in [half*32, half*32+32)).
// Pair threads are adjacent lanes of the same wave -> in-place state update safe.
// Zeroes agg after consuming it (ready for next propagation step).
__global__ __launch_bounds__(256) void gru_cell(
    const float* __restrict__ Wiht, const float* __restrict__ bih,
    const float* __restrict__ Whht, const float* __restrict__ bhh,
    float* __restrict__ state, float* __restrict__ agg)
{
    int tid = blockIdx.x * 256 + threadIdx.x;
    int n = tid >> 1;
    int half = tid & 1;
    if (n >= NN) return;

    float x[64], h[64];
    const float4* xa = reinterpret_cast<const float4*>(agg + (size_t)n * 64);
    const float4* ha = reinterpret_cast<const float4*>(state + (size_t)n * 64);
#pragma unroll
    for (int t = 0; t < 16; t++) {
        float4 v = xa[t];
        x[4 * t + 0] = v.x; x[4 * t + 1] = v.y; x[4 * t + 2] = v.z; x[4 * t + 3] = v.w;
    }
#pragma unroll
    for (int t = 0; t < 16; t++) {
        float4 v = ha[t];
        h[4 * t + 0] = v.x; h[4 * t + 1] = v.y; h[4 * t + 2] = v.z; h[4 * t + 3] = v.w;
    }

    int j0 = half * 32;
    for (int jj = 0; jj < 32; jj++) {
        int j = j0 + jj;
        float ir = bih[j], iz = bih[64 + j], inn = bih[128 + j];
        float hr = bhh[j], hz = bhh[64 + j], hn = bhh[128 + j];
        const float* wir = Wiht + (size_t)j * 64;
        const float* wiz = Wiht + (size_t)(64 + j) * 64;
        const float* win = Wiht + (size_t)(128 + j) * 64;
        const float* whr = Whht + (size_t)j * 64;
        const float* whz = Whht + (size_t)(64 + j) * 64;
        const float* whn = Whht + (size_t)(128 + j) * 64;
#pragma unroll
        for (int k = 0; k < 64; k++) {
            float xk = x[k], hk = h[k];
            ir += xk * wir[k];
            iz += xk * wiz[k];
            inn += xk * win[k];
            hr += hk * whr[k];
            hz += hk * whz[k];
            hn += hk * whn[k];
        }
        float r = 1.f / (1.f + __expf(-(ir + hr)));
        float z = 1.f / (1.f + __expf(-(iz + hz)));
        float ng = tanhf(inn + r * hn);
        float hj = state[(size_t)n * 64 + j];   // avoid runtime-indexed reg array
        float outv = (1.f - z) * ng + z * hj;
        state[(size_t)n * 64 + j] = outv;
        agg[(size_t)n * 64 + j] = 0.f;          // ready for next step
    }
}

__global__ __launch_bounds__(256) void out_proj(
    const float* __restrict__ state, const float* __restrict__ Wout,
    const float* __restrict__ bout, float* __restrict__ out)
{
    int n = blockIdx.x * 256 + threadIdx.x;
    if (n >= NN) return;
    float a0 = bout[0], a1 = bout[1];
    const float4* sr = reinterpret_cast<const float4*>(state + (size_t)n * 64);
#pragma unroll
    for (int t = 0; t < 16; t++) {
        float4 v = sr[t];
        a0 += v.x * Wout[2 * (4 * t + 0)] + v.y * Wout[2 * (4 * t + 1)]
            + v.z * Wout[2 * (4 * t + 2)] + v.w * Wout[2 * (4 * t + 3)];
        a1 += v.x * Wout[2 * (4 * t + 0) + 1] + v.y * Wout[2 * (4 * t + 1) + 1]
            + v.z * Wout[2 * (4 * t + 2) + 1] + v.w * Wout[2 * (4 * t + 3) + 1];
    }
    out[2 * n] = a0;
    out[2 * n + 1] = a1;
}

extern "C" void kernel_launch(void* const* d_in, const int* in_sizes, int n_in,
                              void* d_out, int out_size, void* d_ws, size_t ws_size,
                              hipStream_t stream)
{
    const int*   msg_node = (const int*)  d_in[0];
    const float* J_msg    = (const float*)d_in[1];
    const float* b        = (const float*)d_in[2];
    // d_in[3] = idx_msg_edge (unused by reference)
    const float* W_in     = (const float*)d_in[4];
    const float* b_in     = (const float*)d_in[5];
    const float* W1       = (const float*)d_in[6];
    const float* b1       = (const float*)d_in[7];
    const float* W2       = (const float*)d_in[8];
    const float* b2       = (const float*)d_in[9];
    const float* W3       = (const float*)d_in[10];
    const float* b3       = (const float*)d_in[11];
    const float* W_ih     = (const float*)d_in[12];
    const float* b_ih     = (const float*)d_in[13];
    const float* W_hh     = (const float*)d_in[14];
    const float* b_hh     = (const float*)d_in[15];
    const float* W_out    = (const float*)d_in[16];
    const float* b_out    = (const float*)d_in[17];

    float* ws    = (float*)d_ws;
    float* state = ws;                       // NN*64
    float* agg   = ws + (size_t)NN * 64;     // NN*64
    float* W2t   = agg + (size_t)NN * 64;    // 4096
    float* Wiht  = W2t + 4096;               // 12288
    float* Whht  = Wiht + 12288;             // 12288

    float* out = (float*)d_out;

    prep_transpose<<<48, 256, 0, stream>>>(W2, W_ih, W_hh, W2t, Wiht, Whht);
    init_state<<<(NN * 64 + 255) / 256, 256, 0, stream>>>(b, W_in, b_in, state, agg);

    for (int p = 0; p < 3; p++) {
        edge_mlp<<<NE / 256, 256, 0, stream>>>(msg_node, J_msg, b,
                                               W1, b1, W2t, b2, W3, b3,
                                               state, agg);
        gru_cell<<<(NN * 2 + 255) / 256, 256, 0, stream>>>(Wiht, b_ih, Whht, b_hh,
                                                           state, agg);
    }
    out_proj<<<(NN + 255) / 256, 256, 0, stream>>>(state, W_out, b_out, out);
}

// Round 2
// 1476.697 us; speedup vs baseline: 6.8263x; 6.8263x over previous
//
#include <hip/hip_runtime.h>
#include <math.h>

#define NN 50000
#define NE 800000

__device__ __forceinline__ float sigm(float x) { return 1.f / (1.f + __expf(-x)); }

// ---------------- prep: rank-3 folded ff rows of W1 ----------------
// h1 += bi*A + bo*B + J*C   (A=r64-r65, B=r133-r132, C=r66-r67-r134+r135)
__global__ __launch_bounds__(64) void prep_wf(const float* __restrict__ W1,
                                              float* __restrict__ wf)
{
    int j = threadIdx.x;
    wf[j]       = W1[64 * 64 + j]  - W1[65 * 64 + j];
    wf[64 + j]  = W1[133 * 64 + j] - W1[132 * 64 + j];
    wf[128 + j] = W1[66 * 64 + j] - W1[67 * 64 + j]
                - W1[134 * 64 + j] + W1[135 * 64 + j];
}

__global__ __launch_bounds__(256) void init_state(
    const float* __restrict__ b, const float* __restrict__ W_in,
    const float* __restrict__ b_in,
    float* __restrict__ state, float* __restrict__ agg)
{
    int idx = blockIdx.x * 256 + threadIdx.x;
    if (idx >= NN * 64) return;
    int n = idx >> 6, j = idx & 63;
    state[idx] = b[n] * (W_in[j] - W_in[64 + j]) + b_in[j];
    agg[idx] = 0.f;
}

// ---------------- CSR build ----------------
__global__ __launch_bounds__(256) void csr_zero(int* __restrict__ cnt, int* __restrict__ cur)
{
    int i = blockIdx.x * 256 + threadIdx.x;
    if (i < NN) { cnt[i] = 0; cur[i] = 0; }
}

__global__ __launch_bounds__(256) void csr_count(const int* __restrict__ mn, int* __restrict__ cnt)
{
    int e = blockIdx.x * 256 + threadIdx.x;
    if (e < NE) atomicAdd(&cnt[mn[2 * e + 1]], 1);
}

__global__ __launch_bounds__(256) void scan_block(const int* __restrict__ cnt,
                                                  int* __restrict__ base, int* __restrict__ bsum)
{
    __shared__ int s[256];
    int i = blockIdx.x * 256 + threadIdx.x;
    int v = (i < NN) ? cnt[i] : 0;
    s[threadIdx.x] = v;
    __syncthreads();
    for (int off = 1; off < 256; off <<= 1) {
        int t = (threadIdx.x >= off) ? s[threadIdx.x - off] : 0;
        __syncthreads();
        s[threadIdx.x] += t;
        __syncthreads();
    }
    if (i < NN) base[i] = s[threadIdx.x] - v;
    if (threadIdx.x == 255) bsum[blockIdx.x] = s[255];
}

__global__ __launch_bounds__(256) void scan_top(int* __restrict__ bsum, int nb)
{
    __shared__ int s[256];
    int t = threadIdx.x;
    int v = (t < nb) ? bsum[t] : 0;
    s[t] = v;
    __syncthreads();
    for (int off = 1; off < 256; off <<= 1) {
        int u = (t >= off) ? s[t - off] : 0;
        __syncthreads();
        s[t] += u;
        __syncthreads();
    }
    if (t < nb) bsum[t] = s[t] - v;   // exclusive, in place
}

__global__ __launch_bounds__(256) void scan_add(int* __restrict__ base, const int* __restrict__ bsum)
{
    int i = blockIdx.x * 256 + threadIdx.x;
    if (i < NN) base[i] += bsum[blockIdx.x];
}

__global__ __launch_bounds__(256) void csr_scatter(const int* __restrict__ mn,
    const int* __restrict__ base, int* __restrict__ cur, int* __restrict__ elist)
{
    int e = blockIdx.x * 256 + threadIdx.x;
    if (e < NE) {
        int n = mn[2 * e + 1];
        int p = base[n] + atomicAdd(&cur[n], 1);
        elist[p] = e;
    }
}

// ---------------- edge MLP: tiled GEMM, 64 edges x 64 cols per block ----------------
#define FMA16(xv, wv)                                                        \
    acc[0][0] += xv.x * wv.x; acc[0][1] += xv.x * wv.y;                      \
    acc[0][2] += xv.x * wv.z; acc[0][3] += xv.x * wv.w;                      \
    acc[1][0] += xv.y * wv.x; acc[1][1] += xv.y * wv.y;                      \
    acc[1][2] += xv.y * wv.z; acc[1][3] += xv.y * wv.w;                      \
    acc[2][0] += xv.z * wv.x; acc[2][1] += xv.z * wv.y;                      \
    acc[2][2] += xv.z * wv.z; acc[2][3] += xv.z * wv.w;                      \
    acc[3][0] += xv.w * wv.x; acc[3][1] += xv.w * wv.y;                      \
    acc[3][2] += xv.w * wv.z; acc[3][3] += xv.w * wv.w;

__global__ __launch_bounds__(256, 2) void edge_mlp_t(
    const int* __restrict__ mn, const float* __restrict__ Jm,
    const float* __restrict__ bb,
    const float* __restrict__ W1, const float* __restrict__ b1,
    const float* __restrict__ W2, const float* __restrict__ b2,
    const float* __restrict__ W3, const float* __restrict__ b3,
    const float* __restrict__ wf,
    const float* __restrict__ state,
    float* __restrict__ medge, float* __restrict__ agg, int use_csr)
{
    __shared__ float xs[64][68];   // K-major x / h1 tile
    __shared__ float ys[64][68];   // K-major s_out / h2 tile
    __shared__ float ws[64][64];   // current 64x64 weight tile
    __shared__ int   sei[64], seo[64];
    __shared__ float sbi[64], sbo[64], sJ[64];

    int tid = threadIdx.x;
    int e0 = blockIdx.x * 64;

    if (tid < 64) {
        int e = e0 + tid;
        int a = mn[2 * e], o = mn[2 * e + 1];
        sei[tid] = a; seo[tid] = o;
        sbi[tid] = bb[a]; sbo[tid] = bb[o]; sJ[tid] = Jm[e];
    }
    __syncthreads();

    {   // stage s_in -> xs, s_out -> ys (transposed to K-major), W1 rows 0..63 -> ws
        int m = tid & 63, c = tid >> 6;
        int ein = sei[m], eo = seo[m];
#pragma unroll
        for (int r = 0; r < 4; r++) {
            int k = c * 4 + r * 16;
            float4 v = *(const float4*)&state[(size_t)ein * 64 + k];
            xs[k + 0][m] = v.x; xs[k + 1][m] = v.y; xs[k + 2][m] = v.z; xs[k + 3][m] = v.w;
            float4 u = *(const float4*)&state[(size_t)eo * 64 + k];
            ys[k + 0][m] = u.x; ys[k + 1][m] = u.y; ys[k + 2][m] = u.z; ys[k + 3][m] = u.w;
        }
        const float4* wsrc = (const float4*)W1;
        float4* wdst = (float4*)ws;
#pragma unroll
        for (int r = 0; r < 4; r++) wdst[tid + 256 * r] = wsrc[tid + 256 * r];
    }
    __syncthreads();

    int tn4 = (tid & 15) * 4, tm4 = (tid >> 4) * 4;
    float acc[4][4];
#pragma unroll
    for (int i = 0; i < 4; i++)
#pragma unroll
        for (int j = 0; j < 4; j++) acc[i][j] = 0.f;

    // layer1a: s_in @ W1[0:64]
#pragma unroll 8
    for (int k = 0; k < 64; k++) {
        float4 xv = *(const float4*)&xs[k][tm4];
        float4 wv = *(const float4*)&ws[k][tn4];
        FMA16(xv, wv)
    }
    __syncthreads();
    {   // restage ws <- W1 rows 68..131
        const float4* wsrc = (const float4*)(W1 + 68 * 64);
        float4* wdst = (float4*)ws;
#pragma unroll
        for (int r = 0; r < 4; r++) wdst[tid + 256 * r] = wsrc[tid + 256 * r];
    }
    __syncthreads();

    // layer1b: s_out @ W1[68:132]
#pragma unroll 8
    for (int k = 0; k < 64; k++) {
        float4 xv = *(const float4*)&ys[k][tm4];
        float4 wv = *(const float4*)&ws[k][tn4];
        FMA16(xv, wv)
    }

    {   // rank-3 ff contribution + bias + relu
        float4 A = *(const float4*)&wf[tn4];
        float4 B = *(const float4*)&wf[64 + tn4];
        float4 C = *(const float4*)&wf[128 + tn4];
        float4 b1v = *(const float4*)&b1[tn4];
        float Av[4] = {A.x, A.y, A.z, A.w};
        float Bv[4] = {B.x, B.y, B.z, B.w};
        float Cv[4] = {C.x, C.y, C.z, C.w};
        float bv[4] = {b1v.x, b1v.y, b1v.z, b1v.w};
#pragma unroll
        for (int i = 0; i < 4; i++) {
            int m = tm4 + i;
            float bi = sbi[m], bo = sbo[m], J = sJ[m];
#pragma unroll
            for (int j = 0; j < 4; j++) {
                float h = acc[i][j] + bi * Av[j] + bo * Bv[j] + J * Cv[j] + bv[j];
                acc[i][j] = fmaxf(h, 0.f);
            }
        }
    }
    __syncthreads();                 // everyone done reading xs(GEMM1a)/ws(W1b)
    {   // h1 -> xs (transposed), restage ws <- W2
#pragma unroll
        for (int i = 0; i < 4; i++)
#pragma unroll
            for (int j = 0; j < 4; j++) xs[tn4 + j][tm4 + i] = acc[i][j];
        const float4* wsrc = (const float4*)W2;
        float4* wdst = (float4*)ws;
#pragma unroll
        for (int r = 0; r < 4; r++) wdst[tid + 256 * r] = wsrc[tid + 256 * r];
    }
    __syncthreads();

    // layer2: h1 @ W2
#pragma unroll
    for (int i = 0; i < 4; i++)
#pragma unroll
        for (int j = 0; j < 4; j++) acc[i][j] = 0.f;
#pragma unroll 8
    for (int k = 0; k < 64; k++) {
        float4 xv = *(const float4*)&xs[k][tm4];
        float4 wv = *(const float4*)&ws[k][tn4];
        FMA16(xv, wv)
    }
    {
        float4 b2v = *(const float4*)&b2[tn4];
        float bv[4] = {b2v.x, b2v.y, b2v.z, b2v.w};
#pragma unroll
        for (int i = 0; i < 4; i++)
#pragma unroll
            for (int j = 0; j < 4; j++) acc[i][j] = fmaxf(acc[i][j] + bv[j], 0.f);
    }
    __syncthreads();
    {   // h2 -> ys (transposed), restage ws <- W3
#pragma unroll
        for (int i = 0; i < 4; i++)
#pragma unroll
            for (int j = 0; j < 4; j++) ys[tn4 + j][tm4 + i] = acc[i][j];
        const float4* wsrc = (const float4*)W3;
        float4* wdst = (float4*)ws;
#pragma unroll
        for (int r = 0; r < 4; r++) wdst[tid + 256 * r] = wsrc[tid + 256 * r];
    }
    __syncthreads();

    // layer3: h2 @ W3
#pragma unroll
    for (int i = 0; i < 4; i++)
#pragma unroll
        for (int j = 0; j < 4; j++) acc[i][j] = 0.f;
#pragma unroll 8
    for (int k = 0; k < 64; k++) {
        float4 xv = *(const float4*)&ys[k][tm4];
        float4 wv = *(const float4*)&ws[k][tn4];
        FMA16(xv, wv)
    }
    {
        float4 b3v = *(const float4*)&b3[tn4];
        float bv[4] = {b3v.x, b3v.y, b3v.z, b3v.w};
#pragma unroll
        for (int i = 0; i < 4; i++)
#pragma unroll
            for (int j = 0; j < 4; j++) acc[i][j] += bv[j];
    }

    if (use_csr) {
#pragma unroll
        for (int i = 0; i < 4; i++) {
            int e = e0 + tm4 + i;
            float4 v; v.x = acc[i][0]; v.y = acc[i][1]; v.z = acc[i][2]; v.w = acc[i][3];
            *(float4*)&medge[(size_t)e * 64 + tn4] = v;
        }
    } else {
#pragma unroll
        for (int i = 0; i < 4; i++) {
            float* ar = agg + (size_t)seo[tm4 + i] * 64 + tn4;
#pragma unroll
            for (int j = 0; j < 4; j++) atomicAdd(ar + j, acc[i][j]);
        }
    }
}

// ---------------- segment-sum via CSR gather ----------------
__global__ __launch_bounds__(256) void agg_gather(const float* __restrict__ medge,
    const int* __restrict__ base, const int* __restrict__ cnt,
    const int* __restrict__ elist, float* __restrict__ agg)
{
    int t = blockIdx.x * 256 + threadIdx.x;
    int n = t >> 2;
    if (n >= NN) return;
    int c16 = (t & 3) * 16;
    float4 a0 = make_float4(0.f, 0.f, 0.f, 0.f), a1 = a0, a2 = a0, a3 = a0;
    int b0 = base[n], k = cnt[n];
    for (int i = 0; i < k; i++) {
        int e = elist[b0 + i];
        const float4* mp = (const float4*)&medge[(size_t)e * 64 + c16];
        float4 v0 = mp[0], v1 = mp[1], v2 = mp[2], v3 = mp[3];
        a0.x += v0.x; a0.y += v0.y; a0.z += v0.z; a0.w += v0.w;
        a1.x += v1.x; a1.y += v1.y; a1.z += v1.z; a1.w += v1.w;
        a2.x += v2.x; a2.y += v2.y; a2.z += v2.z; a2.w += v2.w;
        a3.x += v3.x; a3.y += v3.y; a3.z += v3.z; a3.w += v3.w;
    }
    float4* ap = (float4*)&agg[(size_t)n * 64 + c16];
    ap[0] = a0; ap[1] = a1; ap[2] = a2; ap[3] = a3;
}

// ---------------- GRU: gi = agg@W_ih, gh = state@W_hh (tiled) ----------------
__global__ __launch_bounds__(256, 2) void gru_gemm(
    const float* __restrict__ agg, const float* __restrict__ state,
    const float* __restrict__ Wih, const float* __restrict__ Whh,
    float* __restrict__ gi, float* __restrict__ gh)
{
    __shared__ float xa[64][64];
    __shared__ float xh[64][64];
    __shared__ float wi[64][64];
    __shared__ float wh[64][64];

    int tid = threadIdx.x;
    int tile = blockIdx.x / 3, ct = blockIdx.x % 3;
    int n0 = tile * 64, c0 = ct * 64;

    {
        int m = tid & 63, c = tid >> 6;
        int n = n0 + m;
        bool ok = (n < NN);
#pragma unroll
        for (int r = 0; r < 4; r++) {
            int k = c * 4 + r * 16;
            float4 v = ok ? *(const float4*)&agg[(size_t)n * 64 + k]
                          : make_float4(0.f, 0.f, 0.f, 0.f);
            xa[k + 0][m] = v.x; xa[k + 1][m] = v.y; xa[k + 2][m] = v.z; xa[k + 3][m] = v.w;
            float4 u = ok ? *(const float4*)&state[(size_t)n * 64 + k]
                          : make_float4(0.f, 0.f, 0.f, 0.f);
            xh[k + 0][m] = u.x; xh[k + 1][m] = u.y; xh[k + 2][m] = u.z; xh[k + 3][m] = u.w;
        }
#pragma unroll
        for (int r = 0; r < 4; r++) {
            int idx = tid + 256 * r;
            int k = idx >> 4, q = (idx & 15) * 4;
            *(float4*)&wi[k][q] = *(const float4*)&Wih[(size_t)k * 192 + c0 + q];
            *(float4*)&wh[k][q] = *(const float4*)&Whh[(size_t)k * 192 + c0 + q];
        }
    }
    __syncthreads();

    int tn4 = (tid & 15) * 4, tm4 = (tid >> 4) * 4;
    float ai[4][4], ah[4][4];
#pragma unroll
    for (int i = 0; i < 4; i++)
#pragma unroll
        for (int j = 0; j < 4; j++) { ai[i][j] = 0.f; ah[i][j] = 0.f; }

#pragma unroll 4
    for (int k = 0; k < 64; k++) {
        float4 av = *(const float4*)&xa[k][tm4];
        float4 hv = *(const float4*)&xh[k][tm4];
        float4 iv = *(const float4*)&wi[k][tn4];
        float4 vv = *(const float4*)&wh[k][tn4];
        ai[0][0] += av.x * iv.x; ai[0][1] += av.x * iv.y; ai[0][2] += av.x * iv.z; ai[0][3] += av.x * iv.w;
        ai[1][0] += av.y * iv.x; ai[1][1] += av.y * iv.y; ai[1][2] += av.y * iv.z; ai[1][3] += av.y * iv.w;
        ai[2][0] += av.z * iv.x; ai[2][1] += av.z * iv.y; ai[2][2] += av.z * iv.z; ai[2][3] += av.z * iv.w;
        ai[3][0] += av.w * iv.x; ai[3][1] += av.w * iv.y; ai[3][2] += av.w * iv.z; ai[3][3] += av.w * iv.w;
        ah[0][0] += hv.x * vv.x; ah[0][1] += hv.x * vv.y; ah[0][2] += hv.x * vv.z; ah[0][3] += hv.x * vv.w;
        ah[1][0] += hv.y * vv.x; ah[1][1] += hv.y * vv.y; ah[1][2] += hv.y * vv.z; ah[1][3] += hv.y * vv.w;
        ah[2][0] += hv.z * vv.x; ah[2][1] += hv.z * vv.y; ah[2][2] += hv.z * vv.z; ah[2][3] += hv.z * vv.w;
        ah[3][0] += hv.w * vv.x; ah[3][1] += hv.w * vv.y; ah[3][2] += hv.w * vv.z; ah[3][3] += hv.w * vv.w;
    }

#pragma unroll
    for (int i = 0; i < 4; i++) {
        int n = n0 + tm4 + i;
        if (n < NN) {
            float4 v; v.x = ai[i][0]; v.y = ai[i][1]; v.z = ai[i][2]; v.w = ai[i][3];
            *(float4*)&gi[(size_t)n * 192 + c0 + tn4] = v;
            float4 u; u.x = ah[i][0]; u.y = ah[i][1]; u.z = ah[i][2]; u.w = ah[i][3];
            *(float4*)&gh[(size_t)n * 192 + c0 + tn4] = u;
        }
    }
}

__global__ __launch_bounds__(256) void gru_gate(
    const float* __restrict__ gi, const float* __restrict__ gh,
    const float* __restrict__ bih, const float* __restrict__ bhh,
    float* __restrict__ state, float* __restrict__ agg, int zero_agg)
{
    int t = blockIdx.x * 256 + threadIdx.x;
    int n = t >> 6;
    if (n >= NN) return;
    int j = t & 63;
    size_t gb = (size_t)n * 192;
    float ir = gi[gb + j] + bih[j];
    float iz = gi[gb + 64 + j] + bih[64 + j];
    float in_ = gi[gb + 128 + j] + bih[128 + j];
    float hr = gh[gb + j] + bhh[j];
    float hz = gh[gb + 64 + j] + bhh[64 + j];
    float hn = gh[gb + 128 + j] + bhh[128 + j];
    float r = sigm(ir + hr);
    float z = sigm(iz + hz);
    float ng = tanhf(in_ + r * hn);
    size_t si = (size_t)n * 64 + j;
    float h = state[si];
    state[si] = (1.f - z) * ng + z * h;
    if (zero_agg) agg[si] = 0.f;
}

__global__ __launch_bounds__(256) void out_proj(
    const float* __restrict__ state, const float* __restrict__ Wout,
    const float* __restrict__ bout, float* __restrict__ out)
{
    int n = blockIdx.x * 256 + threadIdx.x;
    if (n >= NN) return;
    float a0 = bout[0], a1 = bout[1];
    const float4* sr = (const float4*)(state + (size_t)n * 64);
#pragma unroll
    for (int t = 0; t < 16; t++) {
        float4 v = sr[t];
        a0 += v.x * Wout[2 * (4 * t + 0)] + v.y * Wout[2 * (4 * t + 1)]
            + v.z * Wout[2 * (4 * t + 2)] + v.w * Wout[2 * (4 * t + 3)];
        a1 += v.x * Wout[2 * (4 * t + 0) + 1] + v.y * Wout[2 * (4 * t + 1) + 1]
            + v.z * Wout[2 * (4 * t + 2) + 1] + v.w * Wout[2 * (4 * t + 3) + 1];
    }
    out[2 * n] = a0;
    out[2 * n + 1] = a1;
}

extern "C" void kernel_launch(void* const* d_in, const int* in_sizes, int n_in,
                              void* d_out, int out_size, void* d_ws, size_t ws_size,
                              hipStream_t stream)
{
    const int*   msg_node = (const int*)  d_in[0];
    const float* J_msg    = (const float*)d_in[1];
    const float* b        = (const float*)d_in[2];
    const float* W_in     = (const float*)d_in[4];
    const float* b_in     = (const float*)d_in[5];
    const float* W1       = (const float*)d_in[6];
    const float* b1       = (const float*)d_in[7];
    const float* W2       = (const float*)d_in[8];
    const float* b2       = (const float*)d_in[9];
    const float* W3       = (const float*)d_in[10];
    const float* b3       = (const float*)d_in[11];
    const float* W_ih     = (const float*)d_in[12];
    const float* b_ih     = (const float*)d_in[13];
    const float* W_hh     = (const float*)d_in[14];
    const float* b_hh     = (const float*)d_in[15];
    const float* W_out    = (const float*)d_in[16];
    const float* b_out    = (const float*)d_in[17];

    float* f = (float*)d_ws;
    float* state = f;
    float* agg   = f + (size_t)NN * 64;
    float* big   = agg + (size_t)NN * 64;

    // CSR-path footprint: state/agg + medge + wf + ints(base,cnt,cur,bsum,elist)
    size_t csr_floats = (size_t)NN * 128 + (size_t)NE * 64 + 192;
    size_t csr_ints   = 3 * (size_t)NN + 512 + (size_t)NE;
    size_t csr_bytes  = (csr_floats + csr_ints) * 4;
    int use_csr = (ws_size >= csr_bytes) ? 1 : 0;

    size_t bigsz = use_csr ? (size_t)NE * 64 : (size_t)NN * 384;
    float* medge = big;                       // CSR path only
    float* gi    = big;                       // aliases medge (dead by then)
    float* gh    = big + (size_t)NN * 192;
    float* wf    = big + bigsz;
    int* ip     = (int*)(wf + 192);
    int* cbase  = ip;
    int* ccnt   = ip + NN;
    int* ccur   = ip + 2 * NN;
    int* cbsum  = ip + 3 * NN;                // 512 slots
    int* elist  = ip + 3 * NN + 512;

    prep_wf<<<1, 64, 0, stream>>>(W1, wf);
    init_state<<<(NN * 64 + 255) / 256, 256, 0, stream>>>(b, W_in, b_in, state, agg);

    if (use_csr) {
        csr_zero<<<(NN + 255) / 256, 256, 0, stream>>>(ccnt, ccur);
        csr_count<<<(NE + 255) / 256, 256, 0, stream>>>(msg_node, ccnt);
        scan_block<<<(NN + 255) / 256, 256, 0, stream>>>(ccnt, cbase, cbsum);
        scan_top<<<1, 256, 0, stream>>>(cbsum, (NN + 255) / 256);
        scan_add<<<(NN + 255) / 256, 256, 0, stream>>>(cbase, cbsum);
        csr_scatter<<<(NE + 255) / 256, 256, 0, stream>>>(msg_node, cbase, ccur, elist);
    }

    for (int p = 0; p < 3; p++) {
        edge_mlp_t<<<NE / 64, 256, 0, stream>>>(msg_node, J_msg, b,
                                                W1, b1, W2, b2, W3, b3, wf,
                                                state, medge, agg, use_csr);
        if (use_csr)
            agg_gather<<<(NN * 4 + 255) / 256, 256, 0, stream>>>(medge, cbase, ccnt, elist, agg);
        gru_gemm<<<((NN + 63) / 64) * 3, 256, 0, stream>>>(agg, state, W_ih, W_hh, gi, gh);
        gru_gate<<<(NN * 64 + 255) / 256, 256, 0, stream>>>(gi, gh, b_ih, b_hh,
                                                            state, agg, use_csr ? 0 : 1);
    }
    out_proj<<<(NN + 255) / 256, 256, 0, stream>>>(state, W_out, b_out, (float*)d_out);
}

// Round 3
// 1031.251 us; speedup vs baseline: 9.7749x; 1.4319x over previous
//
#include <hip/hip_runtime.h>
#include <math.h>

#define NN 50000
#define NE 800000

__device__ __forceinline__ float sigm(float x) { return 1.f / (1.f + __expf(-x)); }

// ---------------- prep: folded ff rows of W1 ----------------
// wf[0:64]=A (Pin term), wf[64:128]=B (Pout term), wf[128:192]=C (J term)
__global__ __launch_bounds__(64) void prep_wf(const float* __restrict__ W1,
                                              float* __restrict__ wf)
{
    int j = threadIdx.x;
    wf[j]       = W1[64 * 64 + j]  - W1[65 * 64 + j];
    wf[64 + j]  = W1[133 * 64 + j] - W1[132 * 64 + j];
    wf[128 + j] = W1[66 * 64 + j] - W1[67 * 64 + j]
                - W1[134 * 64 + j] + W1[135 * 64 + j];
}

__global__ __launch_bounds__(256) void init_state(
    const float* __restrict__ b, const float* __restrict__ W_in,
    const float* __restrict__ b_in,
    float* __restrict__ state, float* __restrict__ agg)
{
    int idx = blockIdx.x * 256 + threadIdx.x;
    if (idx >= NN * 64) return;
    int n = idx >> 6, j = idx & 63;
    state[idx] = b[n] * (W_in[j] - W_in[64 + j]) + b_in[j];
    agg[idx] = 0.f;
}

// ---------------- CSR build ----------------
__global__ __launch_bounds__(256) void csr_zero(int* __restrict__ cnt, int* __restrict__ cur)
{
    int i = blockIdx.x * 256 + threadIdx.x;
    if (i < NN) { cnt[i] = 0; cur[i] = 0; }
}

__global__ __launch_bounds__(256) void csr_count(const int* __restrict__ mn, int* __restrict__ cnt)
{
    int e = blockIdx.x * 256 + threadIdx.x;
    if (e < NE) atomicAdd(&cnt[mn[2 * e + 1]], 1);
}

__global__ __launch_bounds__(256) void scan_block(const int* __restrict__ cnt,
                                                  int* __restrict__ base, int* __restrict__ bsum)
{
    __shared__ int s[256];
    int i = blockIdx.x * 256 + threadIdx.x;
    int v = (i < NN) ? cnt[i] : 0;
    s[threadIdx.x] = v;
    __syncthreads();
    for (int off = 1; off < 256; off <<= 1) {
        int t = (threadIdx.x >= off) ? s[threadIdx.x - off] : 0;
        __syncthreads();
        s[threadIdx.x] += t;
        __syncthreads();
    }
    if (i < NN) base[i] = s[threadIdx.x] - v;
    if (threadIdx.x == 255) bsum[blockIdx.x] = s[255];
}

__global__ __launch_bounds__(256) void scan_top(int* __restrict__ bsum, int nb)
{
    __shared__ int s[256];
    int t = threadIdx.x;
    int v = (t < nb) ? bsum[t] : 0;
    s[t] = v;
    __syncthreads();
    for (int off = 1; off < 256; off <<= 1) {
        int u = (t >= off) ? s[t - off] : 0;
        __syncthreads();
        s[t] += u;
        __syncthreads();
    }
    if (t < nb) bsum[t] = s[t] - v;   // exclusive, in place
}

__global__ __launch_bounds__(256) void scan_add(int* __restrict__ base, const int* __restrict__ bsum)
{
    int i = blockIdx.x * 256 + threadIdx.x;
    if (i < NN) base[i] += bsum[blockIdx.x];
}

// writes CSR-permuted edge arrays directly (no elist round-trip)
__global__ __launch_bounds__(256) void csr_scatter_perm(const int* __restrict__ mn,
    const float* __restrict__ Jm,
    const int* __restrict__ base, int* __restrict__ cur,
    int* __restrict__ einP, int* __restrict__ eoutP, float* __restrict__ JP)
{
    int e = blockIdx.x * 256 + threadIdx.x;
    if (e < NE) {
        int n = mn[2 * e + 1];
        int p = base[n] + atomicAdd(&cur[n], 1);
        einP[p]  = mn[2 * e];
        eoutP[p] = n;
        JP[p]    = Jm[e];
    }
}

#define FMA16(xv, wv)                                                        \
    acc[0][0] += xv.x * wv.x; acc[0][1] += xv.x * wv.y;                      \
    acc[0][2] += xv.x * wv.z; acc[0][3] += xv.x * wv.w;                      \
    acc[1][0] += xv.y * wv.x; acc[1][1] += xv.y * wv.y;                      \
    acc[1][2] += xv.y * wv.z; acc[1][3] += xv.y * wv.w;                      \
    acc[2][0] += xv.z * wv.x; acc[2][1] += xv.z * wv.y;                      \
    acc[2][2] += xv.z * wv.z; acc[2][3] += xv.z * wv.w;                      \
    acc[3][0] += xv.w * wv.x; acc[3][1] += xv.w * wv.y;                      \
    acc[3][2] += xv.w * wv.z; acc[3][3] += xv.w * wv.w;

// ---------------- per-node layer-1 projections ----------------
// ct=0: Pin = state@W1[0:64]   + b*A + b1
// ct=1: Pout= state@W1[68:132] + b*B
__global__ __launch_bounds__(256, 2) void node_proj(
    const float* __restrict__ state, const float* __restrict__ bb,
    const float* __restrict__ W1, const float* __restrict__ wf,
    const float* __restrict__ b1,
    float* __restrict__ Pin, float* __restrict__ Pout)
{
    __shared__ float xh[64][68];
    __shared__ float ws[64][64];
    __shared__ float sb[64];

    int tid = threadIdx.x;
    int ct = blockIdx.x & 1;
    int n0 = (blockIdx.x >> 1) * 64;

    const float* Wbase = W1 + (ct ? 68 * 64 : 0);
    float* P = ct ? Pout : Pin;

    {
        int m = tid & 63, cc = tid >> 6;
        int n = n0 + m;
        bool ok = (n < NN);
#pragma unroll
        for (int r = 0; r < 4; r++) {
            int k = cc * 4 + r * 16;
            float4 v = ok ? *(const float4*)&state[(size_t)n * 64 + k]
                          : make_float4(0.f, 0.f, 0.f, 0.f);
            xh[k + 0][m] = v.x; xh[k + 1][m] = v.y; xh[k + 2][m] = v.z; xh[k + 3][m] = v.w;
        }
        const float4* wsrc = (const float4*)Wbase;
        float4* wdst = (float4*)ws;
#pragma unroll
        for (int r = 0; r < 4; r++) wdst[tid + 256 * r] = wsrc[tid + 256 * r];
        if (tid < 64) sb[tid] = (n0 + tid < NN) ? bb[n0 + tid] : 0.f;
    }
    __syncthreads();

    int tn4 = (tid & 15) * 4, tm4 = (tid >> 4) * 4;
    float acc[4][4];
#pragma unroll
    for (int i = 0; i < 4; i++)
#pragma unroll
        for (int j = 0; j < 4; j++) acc[i][j] = 0.f;

#pragma unroll 8
    for (int k = 0; k < 64; k++) {
        float4 xv = *(const float4*)&xh[k][tm4];
        float4 wv = *(const float4*)&ws[k][tn4];
        FMA16(xv, wv)
    }

    float4 Fv = *(const float4*)&wf[ct * 64 + tn4];
    float4 Bv = ct ? make_float4(0.f, 0.f, 0.f, 0.f) : *(const float4*)&b1[tn4];
    float F[4] = {Fv.x, Fv.y, Fv.z, Fv.w};
    float Bi[4] = {Bv.x, Bv.y, Bv.z, Bv.w};
#pragma unroll
    for (int i = 0; i < 4; i++) {
        int n = n0 + tm4 + i;
        if (n < NN) {
            float bn = sb[tm4 + i];
            float4 v;
            v.x = acc[i][0] + bn * F[0] + Bi[0];
            v.y = acc[i][1] + bn * F[1] + Bi[1];
            v.z = acc[i][2] + bn * F[2] + Bi[2];
            v.w = acc[i][3] + bn * F[3] + Bi[3];
            *(float4*)&P[(size_t)n * 64 + tn4] = v;
        }
    }
}

// ---------------- edge MLP (layers 2+3 only), CSR-ordered ----------------
__global__ __launch_bounds__(256, 2) void edge_msg(
    const int* __restrict__ einP, const int* __restrict__ eoutP,
    const float* __restrict__ JP,
    const float* __restrict__ Pin, const float* __restrict__ Pout,
    const float* __restrict__ wf,
    const float* __restrict__ W2, const float* __restrict__ b2,
    const float* __restrict__ W3, const float* __restrict__ b3,
    float* __restrict__ medge, float* __restrict__ agg, int fits)
{
    __shared__ float xs[64][68];   // h1, K-major
    __shared__ float ys[64][68];   // h2, K-major
    __shared__ float ws[64][64];
    __shared__ int   seo[64];

    int tid = threadIdx.x;
    int p0 = blockIdx.x * 64;

    {
        if (tid < 64) seo[tid] = eoutP[p0 + tid];
        int m = tid & 63, cc = tid >> 6;
        int a = einP[p0 + m];
        int o = eoutP[p0 + m];
        float J = JP[p0 + m];
#pragma unroll
        for (int r = 0; r < 4; r++) {
            int k = cc * 4 + r * 16;
            float4 va = *(const float4*)&Pin[(size_t)a * 64 + k];
            float4 vo = *(const float4*)&Pout[(size_t)o * 64 + k];
            float4 vc = *(const float4*)&wf[128 + k];
            xs[k + 0][m] = fmaxf(va.x + vo.x + J * vc.x, 0.f);
            xs[k + 1][m] = fmaxf(va.y + vo.y + J * vc.y, 0.f);
            xs[k + 2][m] = fmaxf(va.z + vo.z + J * vc.z, 0.f);
            xs[k + 3][m] = fmaxf(va.w + vo.w + J * vc.w, 0.f);
        }
        const float4* wsrc = (const float4*)W2;
        float4* wdst = (float4*)ws;
#pragma unroll
        for (int r = 0; r < 4; r++) wdst[tid + 256 * r] = wsrc[tid + 256 * r];
    }
    __syncthreads();

    int tn4 = (tid & 15) * 4, tm4 = (tid >> 4) * 4;
    float acc[4][4];
#pragma unroll
    for (int i = 0; i < 4; i++)
#pragma unroll
        for (int j = 0; j < 4; j++) acc[i][j] = 0.f;

    // layer2: h1 @ W2
#pragma unroll 8
    for (int k = 0; k < 64; k++) {
        float4 xv = *(const float4*)&xs[k][tm4];
        float4 wv = *(const float4*)&ws[k][tn4];
        FMA16(xv, wv)
    }
    {
        float4 b2v = *(const float4*)&b2[tn4];
        float bv[4] = {b2v.x, b2v.y, b2v.z, b2v.w};
#pragma unroll
        for (int i = 0; i < 4; i++)
#pragma unroll
            for (int j = 0; j < 4; j++) acc[i][j] = fmaxf(acc[i][j] + bv[j], 0.f);
    }
    __syncthreads();               // W2/xs readers done
    {
        // h2 -> ys (transposed) as 4x b128 stores
#pragma unroll
        for (int j = 0; j < 4; j++) {
            float4 v; v.x = acc[0][j]; v.y = acc[1][j]; v.z = acc[2][j]; v.w = acc[3][j];
            *(float4*)&ys[tn4 + j][tm4] = v;
        }
        const float4* wsrc = (const float4*)W3;
        float4* wdst = (float4*)ws;
#pragma unroll
        for (int r = 0; r < 4; r++) wdst[tid + 256 * r] = wsrc[tid + 256 * r];
    }
    __syncthreads();

    // layer3: h2 @ W3
#pragma unroll
    for (int i = 0; i < 4; i++)
#pragma unroll
        for (int j = 0; j < 4; j++) acc[i][j] = 0.f;
#pragma unroll 8
    for (int k = 0; k < 64; k++) {
        float4 xv = *(const float4*)&ys[k][tm4];
        float4 wv = *(const float4*)&ws[k][tn4];
        FMA16(xv, wv)
    }
    {
        float4 b3v = *(const float4*)&b3[tn4];
        float bv[4] = {b3v.x, b3v.y, b3v.z, b3v.w};
        if (fits) {
#pragma unroll
            for (int i = 0; i < 4; i++) {
                float4 v;
                v.x = acc[i][0] + bv[0]; v.y = acc[i][1] + bv[1];
                v.z = acc[i][2] + bv[2]; v.w = acc[i][3] + bv[3];
                *(float4*)&medge[(size_t)(p0 + tm4 + i) * 64 + tn4] = v;
            }
        } else {
#pragma unroll
            for (int i = 0; i < 4; i++) {
                float* ar = agg + (size_t)seo[tm4 + i] * 64 + tn4;
#pragma unroll
                for (int j = 0; j < 4; j++) atomicAdd(ar + j, acc[i][j] + bv[j]);
            }
        }
    }
}

// ---------------- segment-sum: fully contiguous (medge in CSR order) ----------------
__global__ __launch_bounds__(256) void agg_gather(const float* __restrict__ medge,
    const int* __restrict__ base, const int* __restrict__ cnt,
    float* __restrict__ agg)
{
    int t = blockIdx.x * 256 + threadIdx.x;
    int n = t >> 2;
    if (n >= NN) return;
    int c16 = (t & 3) * 16;
    float4 a0 = make_float4(0.f, 0.f, 0.f, 0.f), a1 = a0, a2 = a0, a3 = a0;
    int b0 = base[n], k = cnt[n];
    const float4* mp = (const float4*)&medge[(size_t)b0 * 64 + c16];
    for (int i = 0; i < k; i++) {
        float4 v0 = mp[0], v1 = mp[1], v2 = mp[2], v3 = mp[3];
        mp += 16;   // next row (64 floats)
        a0.x += v0.x; a0.y += v0.y; a0.z += v0.z; a0.w += v0.w;
        a1.x += v1.x; a1.y += v1.y; a1.z += v1.z; a1.w += v1.w;
        a2.x += v2.x; a2.y += v2.y; a2.z += v2.z; a2.w += v2.w;
        a3.x += v3.x; a3.y += v3.y; a3.z += v3.z; a3.w += v3.w;
    }
    float4* ap = (float4*)&agg[(size_t)n * 64 + c16];
    ap[0] = a0; ap[1] = a1; ap[2] = a2; ap[3] = a3;
}

// ---------------- GRU ----------------
__global__ __launch_bounds__(256, 2) void gru_gemm(
    const float* __restrict__ agg, const float* __restrict__ state,
    const float* __restrict__ Wih, const float* __restrict__ Whh,
    float* __restrict__ gi, float* __restrict__ gh)
{
    __shared__ float xa[64][64];
    __shared__ float xh[64][64];
    __shared__ float wi[64][64];
    __shared__ float wh[64][64];

    int tid = threadIdx.x;
    int tile = blockIdx.x / 3, ct = blockIdx.x % 3;
    int n0 = tile * 64, c0 = ct * 64;

    {
        int m = tid & 63, c = tid >> 6;
        int n = n0 + m;
        bool ok = (n < NN);
#pragma unroll
        for (int r = 0; r < 4; r++) {
            int k = c * 4 + r * 16;
            float4 v = ok ? *(const float4*)&agg[(size_t)n * 64 + k]
                          : make_float4(0.f, 0.f, 0.f, 0.f);
            xa[k + 0][m] = v.x; xa[k + 1][m] = v.y; xa[k + 2][m] = v.z; xa[k + 3][m] = v.w;
            float4 u = ok ? *(const float4*)&state[(size_t)n * 64 + k]
                          : make_float4(0.f, 0.f, 0.f, 0.f);
            xh[k + 0][m] = u.x; xh[k + 1][m] = u.y; xh[k + 2][m] = u.z; xh[k + 3][m] = u.w;
        }
#pragma unroll
        for (int r = 0; r < 4; r++) {
            int idx = tid + 256 * r;
            int k = idx >> 4, q = (idx & 15) * 4;
            *(float4*)&wi[k][q] = *(const float4*)&Wih[(size_t)k * 192 + c0 + q];
            *(float4*)&wh[k][q] = *(const float4*)&Whh[(size_t)k * 192 + c0 + q];
        }
    }
    __syncthreads();

    int tn4 = (tid & 15) * 4, tm4 = (tid >> 4) * 4;
    float ai[4][4], ah[4][4];
#pragma unroll
    for (int i = 0; i < 4; i++)
#pragma unroll
        for (int j = 0; j < 4; j++) { ai[i][j] = 0.f; ah[i][j] = 0.f; }

#pragma unroll 4
    for (int k = 0; k < 64; k++) {
        float4 av = *(const float4*)&xa[k][tm4];
        float4 hv = *(const float4*)&xh[k][tm4];
        float4 iv = *(const float4*)&wi[k][tn4];
        float4 vv = *(const float4*)&wh[k][tn4];
        ai[0][0] += av.x * iv.x; ai[0][1] += av.x * iv.y; ai[0][2] += av.x * iv.z; ai[0][3] += av.x * iv.w;
        ai[1][0] += av.y * iv.x; ai[1][1] += av.y * iv.y; ai[1][2] += av.y * iv.z; ai[1][3] += av.y * iv.w;
        ai[2][0] += av.z * iv.x; ai[2][1] += av.z * iv.y; ai[2][2] += av.z * iv.z; ai[2][3] += av.z * iv.w;
        ai[3][0] += av.w * iv.x; ai[3][1] += av.w * iv.y; ai[3][2] += av.w * iv.z; ai[3][3] += av.w * iv.w;
        ah[0][0] += hv.x * vv.x; ah[0][1] += hv.x * vv.y; ah[0][2] += hv.x * vv.z; ah[0][3] += hv.x * vv.w;
        ah[1][0] += hv.y * vv.x; ah[1][1] += hv.y * vv.y; ah[1][2] += hv.y * vv.z; ah[1][3] += hv.y * vv.w;
        ah[2][0] += hv.z * vv.x; ah[2][1] += hv.z * vv.y; ah[2][2] += hv.z * vv.z; ah[2][3] += hv.z * vv.w;
        ah[3][0] += hv.w * vv.x; ah[3][1] += hv.w * vv.y; ah[3][2] += hv.w * vv.z; ah[3][3] += hv.w * vv.w;
    }

#pragma unroll
    for (int i = 0; i < 4; i++) {
        int n = n0 + tm4 + i;
        if (n < NN) {
            float4 v; v.x = ai[i][0]; v.y = ai[i][1]; v.z = ai[i][2]; v.w = ai[i][3];
            *(float4*)&gi[(size_t)n * 192 + c0 + tn4] = v;
            float4 u; u.x = ah[i][0]; u.y = ah[i][1]; u.z = ah[i][2]; u.w = ah[i][3];
            *(float4*)&gh[(size_t)n * 192 + c0 + tn4] = u;
        }
    }
}

__global__ __launch_bounds__(256) void gru_gate(
    const float* __restrict__ gi, const float* __restrict__ gh,
    const float* __restrict__ bih, const float* __restrict__ bhh,
    float* __restrict__ state, float* __restrict__ agg, int zero_agg)
{
    int t = blockIdx.x * 256 + threadIdx.x;
    int n = t >> 6;
    if (n >= NN) return;
    int j = t & 63;
    size_t gb = (size_t)n * 192;
    float ir = gi[gb + j] + bih[j];
    float iz = gi[gb + 64 + j] + bih[64 + j];
    float in_ = gi[gb + 128 + j] + bih[128 + j];
    float hr = gh[gb + j] + bhh[j];
    float hz = gh[gb + 64 + j] + bhh[64 + j];
    float hn = gh[gb + 128 + j] + bhh[128 + j];
    float r = sigm(ir + hr);
    float z = sigm(iz + hz);
    float ng = tanhf(in_ + r * hn);
    size_t si = (size_t)n * 64 + j;
    float h = state[si];
    state[si] = (1.f - z) * ng + z * h;
    if (zero_agg) agg[si] = 0.f;
}

__global__ __launch_bounds__(256) void out_proj(
    const float* __restrict__ state, const float* __restrict__ Wout,
    const float* __restrict__ bout, float* __restrict__ out)
{
    int n = blockIdx.x * 256 + threadIdx.x;
    if (n >= NN) return;
    float a0 = bout[0], a1 = bout[1];
    const float4* sr = (const float4*)(state + (size_t)n * 64);
#pragma unroll
    for (int t = 0; t < 16; t++) {
        float4 v = sr[t];
        a0 += v.x * Wout[2 * (4 * t + 0)] + v.y * Wout[2 * (4 * t + 1)]
            + v.z * Wout[2 * (4 * t + 2)] + v.w * Wout[2 * (4 * t + 3)];
        a1 += v.x * Wout[2 * (4 * t + 0) + 1] + v.y * Wout[2 * (4 * t + 1) + 1]
            + v.z * Wout[2 * (4 * t + 2) + 1] + v.w * Wout[2 * (4 * t + 3) + 1];
    }
    out[2 * n] = a0;
    out[2 * n + 1] = a1;
}

extern "C" void kernel_launch(void* const* d_in, const int* in_sizes, int n_in,
                              void* d_out, int out_size, void* d_ws, size_t ws_size,
                              hipStream_t stream)
{
    const int*   msg_node = (const int*)  d_in[0];
    const float* J_msg    = (const float*)d_in[1];
    const float* b        = (const float*)d_in[2];
    const float* W_in     = (const float*)d_in[4];
    const float* b_in     = (const float*)d_in[5];
    const float* W1       = (const float*)d_in[6];
    const float* b1       = (const float*)d_in[7];
    const float* W2       = (const float*)d_in[8];
    const float* b2       = (const float*)d_in[9];
    const float* W3       = (const float*)d_in[10];
    const float* b3       = (const float*)d_in[11];
    const float* W_ih     = (const float*)d_in[12];
    const float* b_ih     = (const float*)d_in[13];
    const float* W_hh     = (const float*)d_in[14];
    const float* b_hh     = (const float*)d_in[15];
    const float* W_out    = (const float*)d_in[16];
    const float* b_out    = (const float*)d_in[17];

    float* f     = (float*)d_ws;
    float* state = f;                                  // NN*64
    float* agg   = state + (size_t)NN * 64;            // NN*64
    float* Pin   = agg   + (size_t)NN * 64;            // NN*64
    float* Pout  = Pin   + (size_t)NN * 64;            // NN*64
    float* wf    = Pout  + (size_t)NN * 64;            // 192
    float* JP    = wf + 192;                           // NE
    int*   einP  = (int*)(JP + NE);                    // NE
    int*   eoutP = einP + NE;                          // NE
    int*   cbase = eoutP + NE;                         // NN
    int*   ccnt  = cbase + NN;                         // NN
    int*   ccur  = ccnt + NN;                          // NN
    int*   cbsum = ccur + NN;                          // 512
    float* medge = (float*)(cbsum + 512);              // NE*64 (fits path)
    float* gi    = medge;                              // aliases medge (dead)
    float* gh    = gi + (size_t)NN * 192;

    size_t fixed_bytes = (size_t)((char*)medge - (char*)d_ws);
    size_t need_fits   = fixed_bytes + (size_t)NE * 64 * 4;
    size_t need_nofits = fixed_bytes + (size_t)NN * 384 * 4;
    int fits = (ws_size >= need_fits) ? 1 : 0;
    (void)need_nofits;

    float* out = (float*)d_out;

    prep_wf<<<1, 64, 0, stream>>>(W1, wf);
    init_state<<<(NN * 64 + 255) / 256, 256, 0, stream>>>(b, W_in, b_in, state, agg);

    csr_zero<<<(NN + 255) / 256, 256, 0, stream>>>(ccnt, ccur);
    csr_count<<<(NE + 255) / 256, 256, 0, stream>>>(msg_node, ccnt);
    scan_block<<<(NN + 255) / 256, 256, 0, stream>>>(ccnt, cbase, cbsum);
    scan_top<<<1, 256, 0, stream>>>(cbsum, (NN + 255) / 256);
    scan_add<<<(NN + 255) / 256, 256, 0, stream>>>(cbase, cbsum);
    csr_scatter_perm<<<(NE + 255) / 256, 256, 0, stream>>>(msg_node, J_msg, cbase, ccur,
                                                           einP, eoutP, JP);

    int ntile = (NN + 63) / 64;
    for (int p = 0; p < 3; p++) {
        node_proj<<<ntile * 2, 256, 0, stream>>>(state, b, W1, wf, b1, Pin, Pout);
        edge_msg<<<NE / 64, 256, 0, stream>>>(einP, eoutP, JP, Pin, Pout, wf,
                                              W2, b2, W3, b3, medge, agg, fits);
        if (fits)
            agg_gather<<<(NN * 4 + 255) / 256, 256, 0, stream>>>(medge, cbase, ccnt, agg);
        gru_gemm<<<ntile * 3, 256, 0, stream>>>(agg, state, W_ih, W_hh, gi, gh);
        gru_gate<<<(NN * 64 + 255) / 256, 256, 0, stream>>>(gi, gh, b_ih, b_hh,
                                                            state, agg, fits ? 0 : 1);
    }
    out_proj<<<(NN + 255) / 256, 256, 0, stream>>>(state, W_out, b_out, out);
}

// Round 5
// 786.606 us; speedup vs baseline: 12.8151x; 1.3110x over previous
//
#include <hip/hip_runtime.h>
#include <math.h>

#define NN 50000
#define NE 800000

typedef __attribute__((ext_vector_type(8))) short bh8;   // 8 bf16 = 4 VGPR (MFMA A/B frag)
typedef __attribute__((ext_vector_type(4))) float fx4;   // MFMA C/D frag

__device__ __forceinline__ short f2b(float x) {
    union { float f; unsigned u; } a; a.f = x;
    unsigned r = a.u + 0x7FFF + ((a.u >> 16) & 1);   // round-to-nearest-even
    return (short)(r >> 16);
}
__device__ __forceinline__ float b2f(short s) {
    union { unsigned u; float f; } a; a.u = ((unsigned)(unsigned short)s) << 16;
    return a.f;
}
__device__ __forceinline__ float sigm(float x) { return 1.f / (1.f + __expf(-x)); }

// ---------------- prep ----------------
// wf[0:64]=A(Pin), wf[64:128]=B(Pout), wf[128:192]=C(J)
__global__ __launch_bounds__(64) void prep_wf(const float* __restrict__ W1,
                                              float* __restrict__ wf)
{
    int j = threadIdx.x;
    wf[j]       = W1[64 * 64 + j]  - W1[65 * 64 + j];
    wf[64 + j]  = W1[133 * 64 + j] - W1[132 * 64 + j];
    wf[128 + j] = W1[66 * 64 + j] - W1[67 * 64 + j]
                - W1[134 * 64 + j] + W1[135 * 64 + j];
}

// W2tB[c*64+k] = bf16(W2[k*64+c]); same for W3
__global__ __launch_bounds__(256) void prep_w23(const float* __restrict__ W2,
                                                const float* __restrict__ W3,
                                                short* __restrict__ W2tB,
                                                short* __restrict__ W3tB)
{
    int i = blockIdx.x * 256 + threadIdx.x;
    if (i < 4096) {
        int c = i >> 6, k = i & 63;
        W2tB[i] = f2b(W2[k * 64 + c]);
        W3tB[i] = f2b(W3[k * 64 + c]);
    }
}

__global__ __launch_bounds__(256) void init_state(
    const float* __restrict__ b, const float* __restrict__ W_in,
    const float* __restrict__ b_in,
    float* __restrict__ state, float* __restrict__ agg)
{
    int idx = blockIdx.x * 256 + threadIdx.x;
    if (idx >= NN * 64) return;
    int n = idx >> 6, j = idx & 63;
    state[idx] = b[n] * (W_in[j] - W_in[64 + j]) + b_in[j];
    agg[idx] = 0.f;
}

// ---------------- CSR build ----------------
__global__ __launch_bounds__(256) void csr_zero(int* __restrict__ cnt, int* __restrict__ cur)
{
    int i = blockIdx.x * 256 + threadIdx.x;
    if (i < NN) { cnt[i] = 0; cur[i] = 0; }
}

__global__ __launch_bounds__(256) void csr_count(const int* __restrict__ mn, int* __restrict__ cnt)
{
    int e = blockIdx.x * 256 + threadIdx.x;
    if (e < NE) atomicAdd(&cnt[mn[2 * e + 1]], 1);
}

__global__ __launch_bounds__(256) void scan_block(const int* __restrict__ cnt,
                                                  int* __restrict__ base, int* __restrict__ bsum)
{
    __shared__ int s[256];
    int i = blockIdx.x * 256 + threadIdx.x;
    int v = (i < NN) ? cnt[i] : 0;
    s[threadIdx.x] = v;
    __syncthreads();
    for (int off = 1; off < 256; off <<= 1) {
        int t = (threadIdx.x >= off) ? s[threadIdx.x - off] : 0;
        __syncthreads();
        s[threadIdx.x] += t;
        __syncthreads();
    }
    if (i < NN) base[i] = s[threadIdx.x] - v;
    if (threadIdx.x == 255) bsum[blockIdx.x] = s[255];
}

__global__ __launch_bounds__(256) void scan_top(int* __restrict__ bsum, int nb)
{
    __shared__ int s[256];
    int t = threadIdx.x;
    int v = (t < nb) ? bsum[t] : 0;
    s[t] = v;
    __syncthreads();
    for (int off = 1; off < 256; off <<= 1) {
        int u = (t >= off) ? s[t - off] : 0;
        __syncthreads();
        s[t] += u;
        __syncthreads();
    }
    if (t < nb) bsum[t] = s[t] - v;
}

__global__ __launch_bounds__(256) void scan_add(int* __restrict__ base, const int* __restrict__ bsum)
{
    int i = blockIdx.x * 256 + threadIdx.x;
    if (i < NN) base[i] += bsum[blockIdx.x];
}

__global__ __launch_bounds__(256) void csr_scatter_perm(const int* __restrict__ mn,
    const float* __restrict__ Jm,
    const int* __restrict__ base, int* __restrict__ cur,
    int* __restrict__ einP, int* __restrict__ eoutP, float* __restrict__ JP)
{
    int e = blockIdx.x * 256 + threadIdx.x;
    if (e < NE) {
        int n = mn[2 * e + 1];
        int p = base[n] + atomicAdd(&cur[n], 1);
        einP[p]  = mn[2 * e];
        eoutP[p] = n;
        JP[p]    = Jm[e];
    }
}

#define FMA16(xv, wv)                                                        \
    acc[0][0] += xv.x * wv.x; acc[0][1] += xv.x * wv.y;                      \
    acc[0][2] += xv.x * wv.z; acc[0][3] += xv.x * wv.w;                      \
    acc[1][0] += xv.y * wv.x; acc[1][1] += xv.y * wv.y;                      \
    acc[1][2] += xv.y * wv.z; acc[1][3] += xv.y * wv.w;                      \
    acc[2][0] += xv.z * wv.x; acc[2][1] += xv.z * wv.y;                      \
    acc[2][2] += xv.z * wv.z; acc[2][3] += xv.z * wv.w;                      \
    acc[3][0] += xv.w * wv.x; acc[3][1] += xv.w * wv.y;                      \
    acc[3][2] += xv.w * wv.z; acc[3][3] += xv.w * wv.w;

// ---------------- per-node layer-1 projections (fp32) ----------------
// ct=0: Pin = state@W1[0:64]   + b*A + b1
// ct=1: Pout= state@W1[68:132] + b*B
__global__ __launch_bounds__(256, 2) void node_proj(
    const float* __restrict__ state, const float* __restrict__ bb,
    const float* __restrict__ W1, const float* __restrict__ wf,
    const float* __restrict__ b1,
    float* __restrict__ Pin, float* __restrict__ Pout)
{
    __shared__ float xh[64][68];
    __shared__ float ws[64][64];
    __shared__ float sb[64];

    int tid = threadIdx.x;
    int ct = blockIdx.x & 1;
    int n0 = (blockIdx.x >> 1) * 64;

    const float* Wbase = W1 + (ct ? 68 * 64 : 0);
    float* P = ct ? Pout : Pin;

    {
        int m = tid & 63, cc = tid >> 6;
        int n = n0 + m;
        bool ok = (n < NN);
#pragma unroll
        for (int r = 0; r < 4; r++) {
            int k = cc * 4 + r * 16;
            float4 v = ok ? *(const float4*)&state[(size_t)n * 64 + k]
                          : make_float4(0.f, 0.f, 0.f, 0.f);
            xh[k + 0][m] = v.x; xh[k + 1][m] = v.y; xh[k + 2][m] = v.z; xh[k + 3][m] = v.w;
        }
        const float4* wsrc = (const float4*)Wbase;
        float4* wdst = (float4*)ws;
#pragma unroll
        for (int r = 0; r < 4; r++) wdst[tid + 256 * r] = wsrc[tid + 256 * r];
        if (tid < 64) sb[tid] = (n0 + tid < NN) ? bb[n0 + tid] : 0.f;
    }
    __syncthreads();

    int tn4 = (tid & 15) * 4, tm4 = (tid >> 4) * 4;
    float acc[4][4];
#pragma unroll
    for (int i = 0; i < 4; i++)
#pragma unroll
        for (int j = 0; j < 4; j++) acc[i][j] = 0.f;

#pragma unroll 8
    for (int k = 0; k < 64; k++) {
        float4 xv = *(const float4*)&xh[k][tm4];
        float4 wv = *(const float4*)&ws[k][tn4];
        FMA16(xv, wv)
    }

    float4 Fv = *(const float4*)&wf[ct * 64 + tn4];
    float4 Bv = ct ? make_float4(0.f, 0.f, 0.f, 0.f) : *(const float4*)&b1[tn4];
    float F[4] = {Fv.x, Fv.y, Fv.z, Fv.w};
    float Bi[4] = {Bv.x, Bv.y, Bv.z, Bv.w};
#pragma unroll
    for (int i = 0; i < 4; i++) {
        int n = n0 + tm4 + i;
        if (n < NN) {
            float bn = sb[tm4 + i];
            float4 v;
            v.x = acc[i][0] + bn * F[0] + Bi[0];
            v.y = acc[i][1] + bn * F[1] + Bi[1];
            v.z = acc[i][2] + bn * F[2] + Bi[2];
            v.w = acc[i][3] + bn * F[3] + Bi[3];
            *(float4*)&P[(size_t)n * 64 + tn4] = v;
        }
    }
}

// ---------------- edge MLP (layers 2+3) via split-precision bf16 MFMA ----------------
// 64 edges x 64 cols per block; 4 waves, wave w owns edge band [16w,16w+16).
// h1/h2 kept f32 in LDS; A-operand split hi+lo (2 MFMAs each) so only W2/W3
// bf16 rounding remains. C/D frag: col=l&15, row=(l>>4)*4+reg (m89-verified).
__global__ __launch_bounds__(256, 3) void edge_msg_mfma(
    const int* __restrict__ einP, const int* __restrict__ eoutP,
    const float* __restrict__ JP,
    const float* __restrict__ Pin, const float* __restrict__ Pout,
    const float* __restrict__ wf,
    const short* __restrict__ W2tB, const float* __restrict__ b2,
    const short* __restrict__ W3tB, const float* __restrict__ b3,
    float* __restrict__ medge, float* __restrict__ agg, int fits)
{
    __shared__ float h1f[64][68];   // h1 f32 (later reused for m output, band-private)
    __shared__ float h2f[64][68];   // h2 f32
    __shared__ short w2s[64][72];   // W2^T [col][k] bf16
    __shared__ short w3s[64][72];   // W3^T [col][k] bf16

    int tid = threadIdx.x;
    int p0 = blockIdx.x * 64;

    // ---- stage: h1 = relu(Pin[a] + Pout[o] + J*C) f32 -> LDS; W2t/W3t -> LDS ----
    {
        int m = tid & 63, kb = (tid >> 6) * 16;
        int a = einP[p0 + m], o = eoutP[p0 + m];
        float J = JP[p0 + m];
#pragma unroll
        for (int q = 0; q < 4; q++) {
            float4 va = *(const float4*)&Pin[(size_t)a * 64 + kb + 4 * q];
            float4 vo = *(const float4*)&Pout[(size_t)o * 64 + kb + 4 * q];
            float4 vc = *(const float4*)&wf[128 + kb + 4 * q];
            float4 r;
            r.x = fmaxf(va.x + vo.x + J * vc.x, 0.f);
            r.y = fmaxf(va.y + vo.y + J * vc.y, 0.f);
            r.z = fmaxf(va.z + vo.z + J * vc.z, 0.f);
            r.w = fmaxf(va.w + vo.w + J * vc.w, 0.f);
            *(float4*)&h1f[m][kb + 4 * q] = r;
        }
        int row = tid >> 2, cb = (tid & 3) * 16;
        *(bh8*)&w2s[row][cb]     = *(const bh8*)&W2tB[row * 64 + cb];
        *(bh8*)&w2s[row][cb + 8] = *(const bh8*)&W2tB[row * 64 + cb + 8];
        *(bh8*)&w3s[row][cb]     = *(const bh8*)&W3tB[row * 64 + cb];
        *(bh8*)&w3s[row][cb + 8] = *(const bh8*)&W3tB[row * 64 + cb + 8];
    }
    __syncthreads();

    int w = tid >> 6, l = tid & 63;
    int lr = l & 15, lg = l >> 4;

    float b2v[4], b3v[4];
#pragma unroll
    for (int ct = 0; ct < 4; ct++) { b2v[ct] = b2[ct * 16 + lr]; b3v[ct] = b3[ct * 16 + lr]; }

    // ---- GEMM2: h2 = relu(h1 @ W2 + b2), A split hi+lo ----
    {
        float va[8], vb[8];
        *(float4*)&va[0] = *(const float4*)&h1f[16 * w + lr][lg * 8];
        *(float4*)&va[4] = *(const float4*)&h1f[16 * w + lr][lg * 8 + 4];
        *(float4*)&vb[0] = *(const float4*)&h1f[16 * w + lr][lg * 8 + 32];
        *(float4*)&vb[4] = *(const float4*)&h1f[16 * w + lr][lg * 8 + 36];
        bh8 Ahi1, Alo1, Ahi2, Alo2;
#pragma unroll
        for (int j = 0; j < 8; j++) {
            short h = f2b(va[j]); Ahi1[j] = h; Alo1[j] = f2b(va[j] - b2f(h));
            short g = f2b(vb[j]); Ahi2[j] = g; Alo2[j] = f2b(vb[j] - b2f(g));
        }
#pragma unroll
        for (int ct = 0; ct < 4; ct++) {
            bh8 B1 = *(const bh8*)&w2s[16 * ct + lr][lg * 8];
            bh8 B2 = *(const bh8*)&w2s[16 * ct + lr][lg * 8 + 32];
            fx4 acc = {0.f, 0.f, 0.f, 0.f};
            acc = __builtin_amdgcn_mfma_f32_16x16x32_bf16(Ahi1, B1, acc, 0, 0, 0);
            acc = __builtin_amdgcn_mfma_f32_16x16x32_bf16(Alo1, B1, acc, 0, 0, 0);
            acc = __builtin_amdgcn_mfma_f32_16x16x32_bf16(Ahi2, B2, acc, 0, 0, 0);
            acc = __builtin_amdgcn_mfma_f32_16x16x32_bf16(Alo2, B2, acc, 0, 0, 0);
#pragma unroll
            for (int r = 0; r < 4; r++)
                h2f[16 * w + 4 * lg + r][16 * ct + lr] = fmaxf(acc[r] + b2v[ct], 0.f);
        }
    }

    // ---- GEMM3: m = h2 @ W3 + b3 (same-wave band through LDS) ----
    {
        float va[8], vb[8];
        *(float4*)&va[0] = *(const float4*)&h2f[16 * w + lr][lg * 8];
        *(float4*)&va[4] = *(const float4*)&h2f[16 * w + lr][lg * 8 + 4];
        *(float4*)&vb[0] = *(const float4*)&h2f[16 * w + lr][lg * 8 + 32];
        *(float4*)&vb[4] = *(const float4*)&h2f[16 * w + lr][lg * 8 + 36];
        bh8 Chi1, Clo1, Chi2, Clo2;
#pragma unroll
        for (int j = 0; j < 8; j++) {
            short h = f2b(va[j]); Chi1[j] = h; Clo1[j] = f2b(va[j] - b2f(h));
            short g = f2b(vb[j]); Chi2[j] = g; Clo2[j] = f2b(vb[j] - b2f(g));
        }
#pragma unroll
        for (int ct = 0; ct < 4; ct++) {
            bh8 B1 = *(const bh8*)&w3s[16 * ct + lr][lg * 8];
            bh8 B2 = *(const bh8*)&w3s[16 * ct + lr][lg * 8 + 32];
            fx4 acc = {0.f, 0.f, 0.f, 0.f};
            acc = __builtin_amdgcn_mfma_f32_16x16x32_bf16(Chi1, B1, acc, 0, 0, 0);
            acc = __builtin_amdgcn_mfma_f32_16x16x32_bf16(Clo1, B1, acc, 0, 0, 0);
            acc = __builtin_amdgcn_mfma_f32_16x16x32_bf16(Chi2, B2, acc, 0, 0, 0);
            acc = __builtin_amdgcn_mfma_f32_16x16x32_bf16(Clo2, B2, acc, 0, 0, 0);
#pragma unroll
            for (int r = 0; r < 4; r++)
                h1f[16 * w + 4 * lg + r][16 * ct + lr] = acc[r] + b3v[ct];   // reuse own band
        }
    }

    // ---- coalesced f32 store of own band (no barrier: band-private, same wave) ----
    {
        int e = 16 * w + (l >> 2), cb = (l & 3) * 16;
        if (fits) {
#pragma unroll
            for (int q = 0; q < 4; q++)
                *(float4*)&medge[(size_t)(p0 + e) * 64 + cb + 4 * q] =
                    *(const float4*)&h1f[e][cb + 4 * q];
        } else {
            int n = eoutP[p0 + e];
#pragma unroll
            for (int j = 0; j < 16; j++)
                atomicAdd(&agg[(size_t)n * 64 + cb + j], h1f[e][cb + j]);
        }
    }
}

// ---------------- segment-sum: contiguous f32 rows ----------------
__global__ __launch_bounds__(256) void agg_gather(const float* __restrict__ medge,
    const int* __restrict__ base, const int* __restrict__ cnt,
    float* __restrict__ agg)
{
    int t = blockIdx.x * 256 + threadIdx.x;
    int n = t >> 2;
    if (n >= NN) return;
    int c16 = (t & 3) * 16;
    float4 a0 = make_float4(0.f, 0.f, 0.f, 0.f), a1 = a0, a2 = a0, a3 = a0;
    int b0 = base[n], k = cnt[n];
    const float4* mp = (const float4*)&medge[(size_t)b0 * 64 + c16];
    for (int i = 0; i < k; i++) {
        float4 v0 = mp[0], v1 = mp[1], v2 = mp[2], v3 = mp[3];
        mp += 16;
        a0.x += v0.x; a0.y += v0.y; a0.z += v0.z; a0.w += v0.w;
        a1.x += v1.x; a1.y += v1.y; a1.z += v1.z; a1.w += v1.w;
        a2.x += v2.x; a2.y += v2.y; a2.z += v2.z; a2.w += v2.w;
        a3.x += v3.x; a3.y += v3.y; a3.z += v3.z; a3.w += v3.w;
    }
    float4* ap = (float4*)&agg[(size_t)n * 64 + c16];
    ap[0] = a0; ap[1] = a1; ap[2] = a2; ap[3] = a3;
}

// ---------------- GRU ----------------
__global__ __launch_bounds__(256, 2) void gru_gemm(
    const float* __restrict__ agg, const float* __restrict__ state,
    const float* __restrict__ Wih, const float* __restrict__ Whh,
    float* __restrict__ gi, float* __restrict__ gh)
{
    __shared__ float xa[64][64];
    __shared__ float xh[64][64];
    __shared__ float wi[64][64];
    __shared__ float wh[64][64];

    int tid = threadIdx.x;
    int tile = blockIdx.x / 3, ct = blockIdx.x % 3;
    int n0 = tile * 64, c0 = ct * 64;

    {
        int m = tid & 63, c = tid >> 6;
        int n = n0 + m;
        bool ok = (n < NN);
#pragma unroll
        for (int r = 0; r < 4; r++) {
            int k = c * 4 + r * 16;
            float4 v = ok ? *(const float4*)&agg[(size_t)n * 64 + k]
                          : make_float4(0.f, 0.f, 0.f, 0.f);
            xa[k + 0][m] = v.x; xa[k + 1][m] = v.y; xa[k + 2][m] = v.z; xa[k + 3][m] = v.w;
            float4 u = ok ? *(const float4*)&state[(size_t)n * 64 + k]
                          : make_float4(0.f, 0.f, 0.f, 0.f);
            xh[k + 0][m] = u.x; xh[k + 1][m] = u.y; xh[k + 2][m] = u.z; xh[k + 3][m] = u.w;
        }
#pragma unroll
        for (int r = 0; r < 4; r++) {
            int idx = tid + 256 * r;
            int k = idx >> 4, q = (idx & 15) * 4;
            *(float4*)&wi[k][q] = *(const float4*)&Wih[(size_t)k * 192 + c0 + q];
            *(float4*)&wh[k][q] = *(const float4*)&Whh[(size_t)k * 192 + c0 + q];
        }
    }
    __syncthreads();

    int tn4 = (tid & 15) * 4, tm4 = (tid >> 4) * 4;
    float ai[4][4], ah[4][4];
#pragma unroll
    for (int i = 0; i < 4; i++)
#pragma unroll
        for (int j = 0; j < 4; j++) { ai[i][j] = 0.f; ah[i][j] = 0.f; }

#pragma unroll 4
    for (int k = 0; k < 64; k++) {
        float4 av = *(const float4*)&xa[k][tm4];
        float4 hv = *(const float4*)&xh[k][tm4];
        float4 iv = *(const float4*)&wi[k][tn4];
        float4 vv = *(const float4*)&wh[k][tn4];
        ai[0][0] += av.x * iv.x; ai[0][1] += av.x * iv.y; ai[0][2] += av.x * iv.z; ai[0][3] += av.x * iv.w;
        ai[1][0] += av.y * iv.x; ai[1][1] += av.y * iv.y; ai[1][2] += av.y * iv.z; ai[1][3] += av.y * iv.w;
        ai[2][0] += av.z * iv.x; ai[2][1] += av.z * iv.y; ai[2][2] += av.z * iv.z; ai[2][3] += av.z * iv.w;
        ai[3][0] += av.w * iv.x; ai[3][1] += av.w * iv.y; ai[3][2] += av.w * iv.z; ai[3][3] += av.w * iv.w;
        ah[0][0] += hv.x * vv.x; ah[0][1] += hv.x * vv.y; ah[0][2] += hv.x * vv.z; ah[0][3] += hv.x * vv.w;
        ah[1][0] += hv.y * vv.x; ah[1][1] += hv.y * vv.y; ah[1][2] += hv.y * vv.z; ah[1][3] += hv.y * vv.w;
        ah[2][0] += hv.z * vv.x; ah[2][1] += hv.z * vv.y; ah[2][2] += hv.z * vv.z; ah[2][3] += hv.z * vv.w;
        ah[3][0] += hv.w * vv.x; ah[3][1] += hv.w * vv.y; ah[3][2] += hv.w * vv.z; ah[3][3] += hv.w * vv.w;
    }

#pragma unroll
    for (int i = 0; i < 4; i++) {
        int n = n0 + tm4 + i;
        if (n < NN) {
            float4 v; v.x = ai[i][0]; v.y = ai[i][1]; v.z = ai[i][2]; v.w = ai[i][3];
            *(float4*)&gi[(size_t)n * 192 + c0 + tn4] = v;
            float4 u; u.x = ah[i][0]; u.y = ah[i][1]; u.z = ah[i][2]; u.w = ah[i][3];
            *(float4*)&gh[(size_t)n * 192 + c0 + tn4] = u;
        }
    }
}

__global__ __launch_bounds__(256) void gru_gate(
    const float* __restrict__ gi, const float* __restrict__ gh,
    const float* __restrict__ bih, const float* __restrict__ bhh,
    float* __restrict__ state, float* __restrict__ agg, int zero_agg)
{
    int t = blockIdx.x * 256 + threadIdx.x;
    int n = t >> 6;
    if (n >= NN) return;
    int j = t & 63;
    size_t gb = (size_t)n * 192;
    float ir = gi[gb + j] + bih[j];
    float iz = gi[gb + 64 + j] + bih[64 + j];
    float in_ = gi[gb + 128 + j] + bih[128 + j];
    float hr = gh[gb + j] + bhh[j];
    float hz = gh[gb + 64 + j] + bhh[64 + j];
    float hn = gh[gb + 128 + j] + bhh[128 + j];
    float r = sigm(ir + hr);
    float z = sigm(iz + hz);
    float ng = tanhf(in_ + r * hn);
    size_t si = (size_t)n * 64 + j;
    float h = state[si];
    state[si] = (1.f - z) * ng + z * h;
    if (zero_agg) agg[si] = 0.f;
}

__global__ __launch_bounds__(256) void out_proj(
    const float* __restrict__ state, const float* __restrict__ Wout,
    const float* __restrict__ bout, float* __restrict__ out)
{
    int n = blockIdx.x * 256 + threadIdx.x;
    if (n >= NN) return;
    float a0 = bout[0], a1 = bout[1];
    const float4* sr = (const float4*)(state + (size_t)n * 64);
#pragma unroll
    for (int t = 0; t < 16; t++) {
        float4 v = sr[t];
        a0 += v.x * Wout[2 * (4 * t + 0)] + v.y * Wout[2 * (4 * t + 1)]
            + v.z * Wout[2 * (4 * t + 2)] + v.w * Wout[2 * (4 * t + 3)];
        a1 += v.x * Wout[2 * (4 * t + 0) + 1] + v.y * Wout[2 * (4 * t + 1) + 1]
            + v.z * Wout[2 * (4 * t + 2) + 1] + v.w * Wout[2 * (4 * t + 3) + 1];
    }
    out[2 * n] = a0;
    out[2 * n + 1] = a1;
}

extern "C" void kernel_launch(void* const* d_in, const int* in_sizes, int n_in,
                              void* d_out, int out_size, void* d_ws, size_t ws_size,
                              hipStream_t stream)
{
    const int*   msg_node = (const int*)  d_in[0];
    const float* J_msg    = (const float*)d_in[1];
    const float* b        = (const float*)d_in[2];
    const float* W_in     = (const float*)d_in[4];
    const float* b_in     = (const float*)d_in[5];
    const float* W1       = (const float*)d_in[6];
    const float* b1       = (const float*)d_in[7];
    const float* W2       = (const float*)d_in[8];
    const float* b2       = (const float*)d_in[9];
    const float* W3       = (const float*)d_in[10];
    const float* b3       = (const float*)d_in[11];
    const float* W_ih     = (const float*)d_in[12];
    const float* b_ih     = (const float*)d_in[13];
    const float* W_hh     = (const float*)d_in[14];
    const float* b_hh     = (const float*)d_in[15];
    const float* W_out    = (const float*)d_in[16];
    const float* b_out    = (const float*)d_in[17];

    float* f     = (float*)d_ws;
    float* state = f;                                  // NN*64 f32
    float* agg   = state + (size_t)NN * 64;            // NN*64 f32
    float* Pin   = agg   + (size_t)NN * 64;            // NN*64 f32
    float* Pout  = Pin   + (size_t)NN * 64;            // NN*64 f32
    float* wf    = Pout  + (size_t)NN * 64;            // 192
    float* JP    = wf + 192;                           // NE
    int*   einP  = (int*)(JP + NE);                    // NE
    int*   eoutP = einP + NE;                          // NE
    int*   cbase = eoutP + NE;                         // NN
    int*   ccnt  = cbase + NN;                         // NN
    int*   ccur  = ccnt + NN;                          // NN
    int*   cbsum = ccur + NN;                          // 512
    short* W2tB  = (short*)(cbsum + 512);              // 4096 bf16
    short* W3tB  = W2tB + 4096;                        // 4096 bf16
    float* medge = (float*)(W3tB + 4096);              // NE*64 f32 (fits path)
    float* gi    = medge;                              // aliases medge (dead by gru)
    float* gh    = gi + (size_t)NN * 192;

    size_t fixed_bytes = (size_t)((char*)medge - (char*)d_ws);
    size_t need_fits   = fixed_bytes + (size_t)NE * 64 * 4;
    size_t need_gru    = fixed_bytes + (size_t)NN * 384 * 4;
    size_t need = need_fits > need_gru ? need_fits : need_gru;
    int fits = (ws_size >= need) ? 1 : 0;

    float* out = (float*)d_out;

    prep_wf<<<1, 64, 0, stream>>>(W1, wf);
    prep_w23<<<16, 256, 0, stream>>>(W2, W3, W2tB, W3tB);
    init_state<<<(NN * 64 + 255) / 256, 256, 0, stream>>>(b, W_in, b_in, state, agg);

    csr_zero<<<(NN + 255) / 256, 256, 0, stream>>>(ccnt, ccur);
    csr_count<<<(NE + 255) / 256, 256, 0, stream>>>(msg_node, ccnt);
    scan_block<<<(NN + 255) / 256, 256, 0, stream>>>(ccnt, cbase, cbsum);
    scan_top<<<1, 256, 0, stream>>>(cbsum, (NN + 255) / 256);
    scan_add<<<(NN + 255) / 256, 256, 0, stream>>>(cbase, cbsum);
    csr_scatter_perm<<<(NE + 255) / 256, 256, 0, stream>>>(msg_node, J_msg, cbase, ccur,
                                                           einP, eoutP, JP);

    int ntile = (NN + 63) / 64;
    for (int p = 0; p < 3; p++) {
        node_proj<<<ntile * 2, 256, 0, stream>>>(state, b, W1, wf, b1, Pin, Pout);
        edge_msg_mfma<<<NE / 64, 256, 0, stream>>>(einP, eoutP, JP, Pin, Pout, wf,
                                                   W2tB, b2, W3tB, b3,
                                                   medge, agg, fits);
        if (fits)
            agg_gather<<<(NN * 4 + 255) / 256, 256, 0, stream>>>(medge, cbase, ccnt, agg);
        gru_gemm<<<ntile * 3, 256, 0, stream>>>(agg, state, W_ih, W_hh, gi, gh);
        gru_gate<<<(NN * 64 + 255) / 256, 256, 0, stream>>>(gi, gh, b_ih, b_hh,
                                                            state, agg, fits ? 0 : 1);
    }
    out_proj<<<(NN + 255) / 256, 256, 0, stream>>>(state, W_out, b_out, out);
}